// Round 9
// baseline (2738.813 us; speedup 1.0000x reference)
//
#include <hip/hip_runtime.h>
#include <math.h>

typedef _Float16 half2_t __attribute__((ext_vector_type(2)));

static constexpr int HID    = 1024;  // hidden size
static constexpr int NGRP   = 16;    // block-groups (each holds one fp16 Wh replica)
static constexpr int GPB    = 16;    // blocks per group; block owns 64 units, wave owns 16
static constexpr int CPG    = 8;     // chains (chunks) interleaved per group
static constexpr int NCHUNK = NGRP * CPG;  // 128 chunks of T
static constexpr int WARM   = 40;    // warmup steps re-deriving state from h=0
static constexpr int NTHR   = 256;   // 4 waves; 1 wave/SIMD -> 512 unified VGPR cap
static constexpr int PCOLS  = 96;    // K_MIX*3*IN_DIM

__device__ __forceinline__ float rcp_fast(float x) { return __builtin_amdgcn_rcpf(x); }
__device__ __forceinline__ float sigmoid_f(float x) { return rcp_fast(1.0f + __expf(-x)); }
__device__ __forceinline__ float tanh_f(float x) {
  const float t = __expf(-2.0f * x);
  return (1.0f - t) * rcp_fast(1.0f + t);
}

__device__ __forceinline__ float dot2h(half2_t a, half2_t b, float c) {
#if __has_builtin(__builtin_amdgcn_fdot2)
  return __builtin_amdgcn_fdot2(a, b, c, false);
#else
  unsigned ua = __builtin_bit_cast(unsigned, a);
  unsigned ub = __builtin_bit_cast(unsigned, b);
  asm("v_dot2_f32_f16 %0, %1, %2, %0" : "+v"(c) : "v"(ua), "v"(ub));
  return c;
#endif
}

// Fold 16 accumulators while reducing across 64 lanes.
// Returns, in lane l, the full 64-lane sum of a[l & 15].
__device__ __forceinline__ float reduce16(const float a[16], int l) {
  const bool m1 = l & 1, m2 = l & 2, m4 = l & 4, m8 = l & 8;
  float b[8];
#pragma unroll
  for (int i = 0; i < 8; ++i)
    b[i] = (m1 ? a[2*i+1] : a[2*i]) + __shfl_xor((m1 ? a[2*i] : a[2*i+1]), 1, 64);
  float c[4];
#pragma unroll
  for (int i = 0; i < 4; ++i)
    c[i] = (m2 ? b[2*i+1] : b[2*i]) + __shfl_xor((m2 ? b[2*i] : b[2*i+1]), 2, 64);
  float d[2];
#pragma unroll
  for (int i = 0; i < 2; ++i)
    d[i] = (m4 ? c[2*i+1] : c[2*i]) + __shfl_xor((m4 ? c[2*i] : c[2*i+1]), 4, 64);
  float e = (m8 ? d[1] : d[0]) + __shfl_xor((m8 ? d[0] : d[1]), 8, 64);
  e += __shfl_xor(e, 16, 64);
  e += __shfl_xor(e, 32, 64);
  return e;
}

__global__ __launch_bounds__(NTHR, 1)
void gru_multichain(const float* __restrict__ ex,   // [T,8]
                    const float* __restrict__ Wx,   // [8,3072]
                    const float* __restrict__ Wh,   // [1024,3072]
                    const float* __restrict__ bx,   // [3072]
                    const float* __restrict__ bh,   // [3072]
                    const float* __restrict__ Wd,   // [1024,96]
                    const float* __restrict__ bd,   // [96]
                    float* __restrict__ out,        // [T,96]
                    unsigned long long* __restrict__ pkt, // [NCHUNK][2][512] {2xfp16 | tag32}, zeroed
                    int T)
{
  const int g   = blockIdx.x & 15;   // group
  const int p   = blockIdx.x >> 4;   // block within group, 0..15
  const int tid = threadIdx.x;
  const int w   = tid >> 6;          // wave 0..3
  const int l   = tid & 63;          // lane

  const int LCH = T / NCHUNK;        // 64
  const int n   = LCH + WARM;        // 104 macro-iterations advance all CPG chains

  __shared__ unsigned pk_s[CPG][2][512];  // per-chain parity-double-buffered h pairs (32 KB)
  __shared__ unsigned wd_s[6 * 512];      // 6 out-proj columns, fp16-pair packed (12 KB)
  __shared__ float    x_s[CPG][8];        // per-chain teacher-forced input

  // ---- Wh slice in registers (fp16 pairs): wave owns units colbase..colbase+15
  const int colbase = 64 * p + 16 * w;
  half2_t whp[16][3][8];
#pragma unroll
  for (int u = 0; u < 16; ++u)
#pragma unroll
    for (int gt = 0; gt < 3; ++gt)
#pragma unroll
      for (int m = 0; m < 8; ++m) {
        const int r0 = 2 * l + 128 * m;
        const size_t col = (size_t)gt * HID + colbase + u;
        half2_t wv;
        wv.x = (_Float16)Wh[(size_t)r0 * 3072 + col];
        wv.y = (_Float16)Wh[(size_t)(r0 + 1) * 3072 + col];
        whp[u][gt][m] = wv;
      }

  // finalize constants for unit myu = colbase + (l&15) (lanes 0..15 finalize)
  const int myu = colbase + (l & 15);
  float wxz[8], wxr_[8], wxc[8];
#pragma unroll
  for (int i = 0; i < 8; ++i) {
    wxz[i]  = Wx[i * 3072 + 0 * HID + myu];
    wxr_[i] = Wx[i * 3072 + 1 * HID + myu];
    wxc[i]  = Wx[i * 3072 + 2 * HID + myu];
  }
  const float bz  = bx[0 * HID + myu] + bh[0 * HID + myu];  // merged pre-sigmoid biases
  const float br  = bx[1 * HID + myu] + bh[1 * HID + myu];
  const float bxc = bx[2 * HID + myu];
  const float bhc = bh[2 * HID + myu];                      // stays inside r*(...)

  // out-projection: waves 0..2 own 2 columns each; Wd fp16-packed in LDS
  const float bdv0 = (w < 3) ? bd[6 * p + 2 * w + 0] : 0.f;
  const float bdv1 = (w < 3) ? bd[6 * p + 2 * w + 1] : 0.f;
  for (int idx = tid; idx < 6 * 512; idx += NTHR) {
    const int cl = idx >> 9, pr = idx & 511;
    const int col = 6 * p + cl;
    half2_t wv;
    wv.x = (_Float16)Wd[(size_t)(2 * pr) * PCOLS + col];
    wv.y = (_Float16)Wd[(size_t)(2 * pr + 1) * PCOLS + col];
    wd_s[idx] = __builtin_bit_cast(unsigned, wv);
  }
  __syncthreads();

  for (int j = 0; j <= n; ++j) {
    const int par = j & 1;

    // ---- poll phase: ALL 16 packet loads issued before any verification
    {
      unsigned long long v[2 * CPG];
#pragma unroll
      for (int s = 0; s < 2 * CPG; ++s) {
        const int c = s >> 1, hf = s & 1;
        v[s] = __hip_atomic_load(
            pkt + (size_t)(g * CPG + c) * 1024 + (size_t)par * 512 + hf * 256 + tid,
            __ATOMIC_RELAXED, __HIP_MEMORY_SCOPE_AGENT);
      }
      const unsigned ju = (unsigned)j;
#pragma unroll
      for (int s = 0; s < 2 * CPG; ++s) {
        const int c = s >> 1, hf = s & 1;
        const unsigned long long* ap =
            pkt + (size_t)(g * CPG + c) * 1024 + (size_t)par * 512 + hf * 256 + tid;
        while ((unsigned)v[s] != ju) {
          __builtin_amdgcn_s_sleep(1);
          v[s] = __hip_atomic_load(ap, __ATOMIC_RELAXED, __HIP_MEMORY_SCOPE_AGENT);
        }
        pk_s[c][par][hf * 256 + tid] = (unsigned)(v[s] >> 32);
      }
    }
    // per-chain teacher-forced input table
    if (tid < CPG * 8) {
      const int c = tid >> 3, i = tid & 7;
      const int t = (g * CPG + c) * LCH - WARM + j;
      x_s[c][i] = (t >= 1) ? ex[(size_t)(t - 1) * 8 + i] : 0.f;
    }
    __syncthreads();  // one barrier per macro-iteration (LDS parity-double-buffered)

    // ---- compute phase: advance each chain by one step (compact runtime loop)
    for (int c = 0; c < CPG; ++c) {
      const int kchain = g * CPG + c;
      const int t = kchain * LCH - WARM + j;  // global step consumed by this chain

      half2_t hh[8];
#pragma unroll
      for (int m = 0; m < 8; ++m)
        hh[m] = __builtin_bit_cast(half2_t, pk_s[c][par][l + 64 * m]);

      if (j < n) {
        // gate-parallel dots: 3 independent accumulator sets -> reduce trees interleave
        float az[16], ar[16], ac[16];
#pragma unroll
        for (int u = 0; u < 16; ++u) { az[u] = 0.f; ar[u] = 0.f; ac[u] = 0.f; }
#pragma unroll
        for (int m = 0; m < 8; ++m)
#pragma unroll
          for (int u = 0; u < 16; ++u) {
            az[u] = dot2h(whp[u][0][m], hh[m], az[u]);
            ar[u] = dot2h(whp[u][1][m], hh[m], ar[u]);
            ac[u] = dot2h(whp[u][2][m], hh[m], ac[u]);
          }
        const float sz = reduce16(az, l);
        const float sr = reduce16(ar, l);
        const float sc = reduce16(ac, l);

        if (l < 16) {
          float gz = 0.f, gr = 0.f, gc = 0.f;
#pragma unroll
          for (int i = 0; i < 8; ++i) {
            const float xi = x_s[c][i];
            gz = fmaf(xi, wxz[i], gz);
            gr = fmaf(xi, wxr_[i], gr);
            gc = fmaf(xi, wxc[i], gc);
          }
          // h_old (fp16) from the staged packet
          const unsigned hw = pk_s[c][par][myu >> 1];
          const unsigned short hs16 =
              (unsigned short)((myu & 1) ? (hw >> 16) : (hw & 0xFFFFu));
          const float hprev = (float)__builtin_bit_cast(_Float16, hs16);

          // Keras GRU reset_after=True, gate order (z, r, h)
          const float z    = sigmoid_f(gz + sz + bz);
          const float r    = sigmoid_f(gr + sr + br);
          const float cand = tanh_f(gc + bxc + r * (sc + bhc));
          float hnew = z * hprev + (1.f - z) * cand;
          if (t < 0) hnew = 0.f;  // chunk 0 pre-roll: keep h(0) == 0 exact

          // pack 2 units/packet: even lane gathers partner's fp16 via 1 shfl, stores 8B
          const unsigned short hb = __builtin_bit_cast(unsigned short, (_Float16)hnew);
          const unsigned hi = (unsigned)__shfl((int)hb, l | 1, 64);
          if ((l & 1) == 0) {
            const unsigned pair = ((hi & 0xFFFFu) << 16) | (unsigned)hb;
            const unsigned long long pv =
                ((unsigned long long)pair << 32) | (unsigned)(j + 1);
            __hip_atomic_store(
                pkt + (size_t)kchain * 1024 + (size_t)(par ^ 1) * 512 + ((colbase + l) >> 1),
                pv, __ATOMIC_RELAXED, __HIP_MEMORY_SCOPE_AGENT);
          }
        }
      }

      // fused output row t-1 (hh = hs[t-1]); after the store => off the serial chain
      if (w < 3) {
        const int tp = t - 1;
        if (tp >= kchain * LCH) {
          float ap0 = 0.f, ap1 = 0.f;
#pragma unroll
          for (int m = 0; m < 8; ++m) {
            const int pr = 64 * m + l;
            ap0 = dot2h(hh[m], __builtin_bit_cast(half2_t, wd_s[(2 * w + 0) * 512 + pr]), ap0);
            ap1 = dot2h(hh[m], __builtin_bit_cast(half2_t, wd_s[(2 * w + 1) * 512 + pr]), ap1);
          }
#pragma unroll
          for (int mm = 32; mm; mm >>= 1) {
            ap0 += __shfl_xor(ap0, mm, 64);
            ap1 += __shfl_xor(ap1, mm, 64);
          }
          if (l == 0) {
            out[(size_t)tp * PCOLS + 6 * p + 2 * w + 0] = ap0 + bdv0;
            out[(size_t)tp * PCOLS + 6 * p + 2 * w + 1] = ap1 + bdv1;
          }
        }
      }
    }
  }
}

extern "C" void kernel_launch(void* const* d_in, const int* in_sizes, int n_in,
                              void* d_out, int out_size, void* d_ws, size_t ws_size,
                              hipStream_t stream)
{
  const float* ex = (const float*)d_in[0];
  const float* Wx = (const float*)d_in[1];
  const float* Wh = (const float*)d_in[2];
  const float* bx = (const float*)d_in[3];
  const float* bh = (const float*)d_in[4];
  const float* Wd = (const float*)d_in[5];
  const float* bd = (const float*)d_in[6];
  float* out = (float*)d_out;
  unsigned long long* pkt = (unsigned long long*)d_ws;
  const int T = in_sizes[0] / 8;

  // zero packets: tag 0 + fp16 h=0 == valid initial state for every chain
  hipMemsetAsync(d_ws, 0, (size_t)NCHUNK * 1024 * sizeof(unsigned long long), stream);
  hipLaunchKernelGGL(gru_multichain, dim3(NGRP * GPB), dim3(NTHR), 0, stream,
                     ex, Wx, Wh, bx, bh, Wd, bd, out, pkt, T);
}

// Round 10
// 912.379 us; speedup vs baseline: 3.0018x; 3.0018x over previous
//
#include <hip/hip_runtime.h>
#include <math.h>

typedef _Float16 half8_t __attribute__((ext_vector_type(8)));
typedef float    f32x4  __attribute__((ext_vector_type(4)));
typedef int      i32x4  __attribute__((ext_vector_type(4)));

static constexpr int HID    = 1024;  // hidden size
static constexpr int NGRP   = 16;    // block-groups (each holds one fp16 Wh replica)
static constexpr int GPB    = 16;    // blocks per group; block owns 64 units, wave owns 16
static constexpr int CPG    = 8;     // chains (chunks) interleaved per group (MFMA M-rows)
static constexpr int NCHUNK = NGRP * CPG;  // 128 chunks of T
static constexpr int WARM   = 40;    // warmup steps re-deriving state from h=0
static constexpr int NTHR   = 256;   // 4 waves; 1 wave/SIMD
static constexpr int PCOLS  = 96;    // K_MIX*3*IN_DIM

__device__ __forceinline__ float rcp_fast(float x) { return __builtin_amdgcn_rcpf(x); }
__device__ __forceinline__ float sigmoid_f(float x) { return rcp_fast(1.0f + __expf(-x)); }
__device__ __forceinline__ float tanh_f(float x) {
  const float t = __expf(-2.0f * x);
  return (1.0f - t) * rcp_fast(1.0f + t);
}

__device__ __forceinline__ float dot2h(half8_t dummy_unused, float c) { return c; }  // (unused helper removed)

typedef _Float16 half2_t __attribute__((ext_vector_type(2)));
__device__ __forceinline__ float dot2(half2_t a, half2_t b, float c) {
#if __has_builtin(__builtin_amdgcn_fdot2)
  return __builtin_amdgcn_fdot2(a, b, c, false);
#else
  unsigned ua = __builtin_bit_cast(unsigned, a);
  unsigned ub = __builtin_bit_cast(unsigned, b);
  asm("v_dot2_f32_f16 %0, %1, %2, %0" : "+v"(c) : "v"(ua), "v"(ub));
  return c;
#endif
}

__global__ __launch_bounds__(NTHR, 1)
void gru_mfma(const float* __restrict__ ex,   // [T,8]
              const float* __restrict__ Wx,   // [8,3072]
              const float* __restrict__ Wh,   // [1024,3072]
              const float* __restrict__ bx,   // [3072]
              const float* __restrict__ bh,   // [3072]
              const float* __restrict__ Wd,   // [1024,96]
              const float* __restrict__ bd,   // [96]
              float* __restrict__ out,        // [T,96]
              unsigned long long* __restrict__ pkt, // [NCHUNK][2][512] {2xfp16 | tag32}, zeroed
              int T)
{
  const int g   = blockIdx.x & 15;   // group
  const int p   = blockIdx.x >> 4;   // block within group, 0..15
  const int tid = threadIdx.x;
  const int w   = tid >> 6;          // wave 0..3
  const int l   = tid & 63;          // lane
  const int cu  = l & 15;            // MFMA col (unit-within-wave) / A-row (chain)
  const int qk  = l >> 4;            // MFMA k-subgroup

  const int LCH = T / NCHUNK;        // 64
  const int n   = LCH + WARM;        // 104 macro-iterations advance all CPG chains

  __shared__ unsigned pk_s[CPG][2][516];  // staged h pairs, padded (+4 dwords) for bank spread (~33KB)
  __shared__ unsigned wd_s[6 * 512];      // 6 out-proj columns, fp16-pair packed (12KB)
  __shared__ float    wx_s[3 * 512];      // Wx slice for block's 64 units: [gate][unit_local][i] (6KB)
  __shared__ float    x_s[CPG][8];        // per-chain teacher-forced input

  // ---- Wh slice as MFMA B-fragments: wave owns units colbase..colbase+15.
  // B-frag (16x16x32): lane holds col = cu, k-rows = qk*8 + jj, per k-step.
  const int colbase = 64 * p + 16 * w;
  half8_t wb[3][32];
#pragma unroll
  for (int gt = 0; gt < 3; ++gt)
#pragma unroll
    for (int k = 0; k < 32; ++k) {
      half8_t v;
#pragma unroll
      for (int jj = 0; jj < 8; ++jj) {
        const int row = k * 32 + qk * 8 + jj;
        v[jj] = (_Float16)Wh[(size_t)row * 3072 + gt * HID + colbase + cu];
      }
      wb[gt][k] = v;
    }

  // finalize constants for unit myu = colbase + cu
  const int myu = colbase + cu;
  const int ul  = 16 * w + cu;  // unit index local to block (0..63)
  const float bz  = bx[0 * HID + myu] + bh[0 * HID + myu];
  const float br  = bx[1 * HID + myu] + bh[1 * HID + myu];
  const float bxc = bx[2 * HID + myu];
  const float bhc = bh[2 * HID + myu];

  // Wx slice -> LDS
  for (int idx = tid; idx < 3 * 512; idx += NTHR) {
    const int gt = idx >> 9, rem = idx & 511, u = rem >> 3, i = rem & 7;
    wx_s[idx] = Wx[(size_t)i * 3072 + gt * HID + 64 * p + u];
  }
  // out-projection: waves 0..2 own 2 columns each; Wd fp16-packed in LDS
  const float bdv0 = (w < 3) ? bd[6 * p + 2 * w + 0] : 0.f;
  const float bdv1 = (w < 3) ? bd[6 * p + 2 * w + 1] : 0.f;
  for (int idx = tid; idx < 6 * 512; idx += NTHR) {
    const int cl = idx >> 9, pr = idx & 511;
    const int col = 6 * p + cl;
    half2_t wv;
    wv.x = (_Float16)Wd[(size_t)(2 * pr) * PCOLS + col];
    wv.y = (_Float16)Wd[(size_t)(2 * pr + 1) * PCOLS + col];
    wd_s[idx] = __builtin_bit_cast(unsigned, wv);
  }
  __syncthreads();

  for (int j = 0; j <= n; ++j) {
    const int par = j & 1;

    // ---- poll phase: ALL 16 packet loads issued before any verification (R9-proven)
    {
      unsigned long long v[16];
#pragma unroll
      for (int s = 0; s < 16; ++s) {
        const int c = s >> 1, hf = s & 1;
        v[s] = __hip_atomic_load(
            pkt + (size_t)(g * CPG + c) * 1024 + (size_t)par * 512 + hf * 256 + tid,
            __ATOMIC_RELAXED, __HIP_MEMORY_SCOPE_AGENT);
      }
      const unsigned ju = (unsigned)j;
#pragma unroll
      for (int s = 0; s < 16; ++s) {
        const int c = s >> 1, hf = s & 1;
        const unsigned long long* ap =
            pkt + (size_t)(g * CPG + c) * 1024 + (size_t)par * 512 + hf * 256 + tid;
        while ((unsigned)v[s] != ju) {
          __builtin_amdgcn_s_sleep(1);
          v[s] = __hip_atomic_load(ap, __ATOMIC_RELAXED, __HIP_MEMORY_SCOPE_AGENT);
        }
        pk_s[c][par][hf * 256 + tid] = (unsigned)(v[s] >> 32);
      }
    }
    if (tid < CPG * 8) {
      const int c = tid >> 3, i = tid & 7;
      const int t = (g * CPG + c) * LCH - WARM + j;
      x_s[c][i] = (t >= 1) ? ex[(size_t)(t - 1) * 8 + i] : 0.f;
    }
    __syncthreads();  // one barrier per macro-iteration (LDS parity-double-buffered)

    if (j < n) {
      // ---- batched recurrent GEMM: A=[16x1024] (8 chains + 8 dup rows), B=wave's [1024x16] per gate
      const int ceff = cu & 7;  // A-row chain (rows 8..15 duplicate 0..7; their C rows unused)
      const unsigned* abase = &pk_s[ceff][par][0];
      f32x4 acc0 = {0.f, 0.f, 0.f, 0.f}, acc1 = acc0, acc2 = acc0;
#pragma unroll
      for (int k = 0; k < 32; ++k) {
        const i32x4 av = *(const i32x4*)(abase + k * 16 + qk * 4);
        const half8_t a = __builtin_bit_cast(half8_t, av);
        acc0 = __builtin_amdgcn_mfma_f32_16x16x32_f16(a, wb[0][k], acc0, 0, 0, 0);
        acc1 = __builtin_amdgcn_mfma_f32_16x16x32_f16(a, wb[1][k], acc1, 0, 0, 0);
        acc2 = __builtin_amdgcn_mfma_f32_16x16x32_f16(a, wb[2][k], acc2, 0, 0, 0);
      }

      // ---- finalize: lanes 0..31 hold C rows 0..7 (chains), col = cu (unit)
      if (l < 32) {
        float wzl[8], wrl[8], wcl[8];
#pragma unroll
        for (int i = 0; i < 8; ++i) {
          wzl[i] = wx_s[0 * 512 + ul * 8 + i];
          wrl[i] = wx_s[1 * 512 + ul * 8 + i];
          wcl[i] = wx_s[2 * 512 + ul * 8 + i];
        }
        float hn[4];
#pragma unroll
        for (int r = 0; r < 4; ++r) {
          const int c  = (l >> 4) * 4 + r;        // chain 0..7
          const int kch = g * CPG + c;
          const int t  = kch * LCH - WARM + j;
          float gz = 0.f, gr = 0.f, gc = 0.f;
#pragma unroll
          for (int i = 0; i < 8; ++i) {
            const float xi = x_s[c][i];
            gz = fmaf(xi, wzl[i], gz);
            gr = fmaf(xi, wrl[i], gr);
            gc = fmaf(xi, wcl[i], gc);
          }
          const unsigned hw = pk_s[c][par][myu >> 1];
          const unsigned short hp16 =
              (unsigned short)((myu & 1) ? (hw >> 16) : (hw & 0xFFFFu));
          const float hprev = (float)__builtin_bit_cast(_Float16, hp16);

          // Keras GRU reset_after=True, gate order (z, r, h)
          const float z    = sigmoid_f(gz + acc0[r] + bz);
          const float rr   = sigmoid_f(gr + acc1[r] + br);
          const float cand = tanh_f(gc + bxc + rr * (acc2[r] + bhc));
          float hnew = z * hprev + (1.f - z) * cand;
          if (t < 0) hnew = 0.f;  // chunk-0 pre-roll keeps h(0) == 0 exact
          hn[r] = hnew;
        }
        // pack 2 units/packet (even unit gathers odd via 1 shfl), 4 stores/lane
#pragma unroll
        for (int r = 0; r < 4; ++r) {
          const unsigned short hb = __builtin_bit_cast(unsigned short, (_Float16)hn[r]);
          const unsigned hi = (unsigned)__shfl((int)hb, l | 1, 64);
          if ((l & 1) == 0) {
            const int c   = (l >> 4) * 4 + r;
            const int kch = g * CPG + c;
            const unsigned pair = ((hi & 0xFFFFu) << 16) | (unsigned)hb;
            const unsigned long long pv =
                ((unsigned long long)pair << 32) | (unsigned)(j + 1);
            __hip_atomic_store(
                pkt + (size_t)kch * 1024 + (size_t)(par ^ 1) * 512 + (myu >> 1),
                pv, __ATOMIC_RELAXED, __HIP_MEMORY_SCOPE_AGENT);
          }
        }
      }
    }

    // ---- fused output rows (pre-step h = hs[t-1]); off the handoff critical path
    if (w < 3) {
#pragma unroll
      for (int c = 0; c < CPG; ++c) {
        const int kch = g * CPG + c;
        const int tp = kch * LCH - WARM + j - 1;
        if (tp >= kch * LCH) {
          float ap0 = 0.f, ap1 = 0.f;
#pragma unroll
          for (int m = 0; m < 8; ++m) {
            const half2_t hv = __builtin_bit_cast(half2_t, pk_s[c][par][l + 64 * m]);
            ap0 = dot2(hv, __builtin_bit_cast(half2_t, wd_s[(2 * w + 0) * 512 + 64 * m + l]), ap0);
            ap1 = dot2(hv, __builtin_bit_cast(half2_t, wd_s[(2 * w + 1) * 512 + 64 * m + l]), ap1);
          }
#pragma unroll
          for (int mm = 32; mm; mm >>= 1) {
            ap0 += __shfl_xor(ap0, mm, 64);
            ap1 += __shfl_xor(ap1, mm, 64);
          }
          if (l == 0) {
            out[(size_t)tp * PCOLS + 6 * p + 2 * w + 0] = ap0 + bdv0;
            out[(size_t)tp * PCOLS + 6 * p + 2 * w + 1] = ap1 + bdv1;
          }
        }
      }
    }
  }
}

extern "C" void kernel_launch(void* const* d_in, const int* in_sizes, int n_in,
                              void* d_out, int out_size, void* d_ws, size_t ws_size,
                              hipStream_t stream)
{
  const float* ex = (const float*)d_in[0];
  const float* Wx = (const float*)d_in[1];
  const float* Wh = (const float*)d_in[2];
  const float* bx = (const float*)d_in[3];
  const float* bh = (const float*)d_in[4];
  const float* Wd = (const float*)d_in[5];
  const float* bd = (const float*)d_in[6];
  float* out = (float*)d_out;
  unsigned long long* pkt = (unsigned long long*)d_ws;
  const int T = in_sizes[0] / 8;

  // zero packets: tag 0 + fp16 h=0 == valid initial state for every chain
  hipMemsetAsync(d_ws, 0, (size_t)NCHUNK * 1024 * sizeof(unsigned long long), stream);
  hipLaunchKernelGGL(gru_mfma, dim3(NGRP * GPB), dim3(NTHR), 0, stream,
                     ex, Wx, Wh, bx, bh, Wd, bd, out, pkt, T);
}